// Round 10
// baseline (326.425 us; speedup 1.0000x reference)
//
#include <hip/hip_runtime.h>

#define NN 512       // nodes
#define BB_ 64       // batch
#define EE 32768     // edges
#define TT 50        // input channels
#define FF 32        // hidden channels
#define NB 2048      // BB_*FF : width of node-major feature rows

typedef _Float16 f16x8 __attribute__((ext_vector_type(8)));
typedef float    f32x4 __attribute__((ext_vector_type(4)));
typedef unsigned short ushort_t;

// ws float offsets (all dedicated, no aliasing; ~27 MB total)
#define OFF_LHAT 0                         // 512*512 f32
#define OFF_LHI  (512 * 512)               // 512*512 u16 = 131072 f
#define OFF_LLO  (OFF_LHI + 131072)        // 131072 f
#define OFF_DEG  (OFF_LLO + 131072)        // 512 f
#define OFF_HP0  (OFF_DEG + 512)           // NN*NB f
#define OFF_HP1  (OFF_HP0 + NN * NB)
#define OFF_GHT  (OFF_HP1 + NN * NB)       // 2048*512 u16 = 524288 f
#define OFF_GLT  (OFF_GHT + 524288)
#define OFF_F0   (OFF_GLT + 524288)        // NN*NB f
#define OFF_P    (OFF_F0 + NN * NB)        // 128*16384 f
#define WS_FLOATS (OFF_P + 128 * 16384)

// ---------------- setup kernels ----------------

__global__ void k_zero_out(float* out, int n) {
    int i = blockIdx.x * blockDim.x + threadIdx.x;
    if (i < n) out[i] = 0.f;
}

__global__ void k_zero_range(float* p, int n) {
    int i = blockIdx.x * blockDim.x + threadIdx.x;
    if (i < n) p[i] = 0.f;
}

__global__ void k_deg(const int* __restrict__ ei, const float* __restrict__ ew,
                      float* __restrict__ deg) {
    int e = blockIdx.x * blockDim.x + threadIdx.x;
    if (e >= EE) return;
    int s = ei[e] & (NN - 1), d = ei[EE + e] & (NN - 1);
    if (s != d) atomicAdd(&deg[s], ew[e]);
}

__global__ void k_dinv(float* deg) {
    int i = threadIdx.x;
    float d = deg[i];
    deg[i] = (d > 0.f) ? rsqrtf(d) : 0.f;
}

__global__ void k_build(const int* __restrict__ ei, const float* __restrict__ ew,
                        const float* __restrict__ dinv, float* __restrict__ Lhat) {
    int e = blockIdx.x * blockDim.x + threadIdx.x;
    if (e >= EE) return;
    int s = ei[e] & (NN - 1), d = ei[EE + e] & (NN - 1);
    if (s == d) return;
    float nm = -(dinv[s] * ew[e] * dinv[d]);
    atomicAdd(&Lhat[d * NN + s], nm);
}

__global__ void k_splitL(const float* __restrict__ L,
                         ushort_t* __restrict__ Lhi, ushort_t* __restrict__ Llo) {
    int i = blockIdx.x * 256 + threadIdx.x;   // 262144 total
    float v = L[i];
    _Float16 h = (_Float16)v;
    _Float16 l = (_Float16)(v - (float)h);
    Lhi[i] = __builtin_bit_cast(ushort_t, h);
    Llo[i] = __builtin_bit_cast(ushort_t, l);
}

// ---------------- small GEMM v3 ----------------
// Ght/Glt[j][k] = split(H W1)^T (j=b*32+f, k=n), F0[n][j] = H W0 + b.
// Block = (batch b, node-group of 128). 256 thr = 8 nq x 32 f; thread owns
// 16 nodes x 1 feature -> contiguous 32B u16 row-writes into Ght/Glt.
template<int CIN, int MODE>
__global__ __launch_bounds__(256) void k_small(
        const float* __restrict__ A0, const float* __restrict__ A1,
        const float* __restrict__ W, const float* __restrict__ bias,
        ushort_t* __restrict__ Ght, ushort_t* __restrict__ Glt,
        float* __restrict__ F0) {
    __shared__ float W0s[CIN * FF];
    __shared__ float W1s[CIN * FF];
    __shared__ float bs[FF];
    __shared__ float rows[128][CIN + 1];
    const int tid = threadIdx.x;
    const int b = blockIdx.x, n0 = blockIdx.y * 128;
    for (int i = tid; i < CIN * FF; i += 256) {
        W0s[i] = W[i];
        W1s[i] = W[CIN * FF + i];
    }
    if (tid < FF) bs[tid] = bias[tid];
    if (MODE == 0) {
        const float* xb = A0 + ((size_t)b * NN + n0) * CIN;
        for (int idx = tid; idx < 128 * CIN; idx += 256)
            rows[idx / CIN][idx % CIN] = xb[idx];
    } else {
        for (int q = tid; q < 128 * 8; q += 256) {     // CIN=32: 8 f4 per row
            int n = q >> 3, c4 = (q & 7) * 4;
            size_t o = (size_t)(n0 + n) * NB + b * FF + c4;
            float4 v0 = *(const float4*)&A0[o];
            float4 v1 = *(const float4*)&A1[o];
            rows[n][c4 + 0] = fmaxf(v0.x + v1.x, 0.f);
            rows[n][c4 + 1] = fmaxf(v0.y + v1.y, 0.f);
            rows[n][c4 + 2] = fmaxf(v0.z + v1.z, 0.f);
            rows[n][c4 + 3] = fmaxf(v0.w + v1.w, 0.f);
        }
    }
    __syncthreads();
    const int f = tid & 31, nq = tid >> 5;
    float gacc[16] = {};
    float facc[16];
#pragma unroll
    for (int i = 0; i < 16; ++i) facc[i] = bs[f];
    for (int c = 0; c < CIN; ++c) {
        float w0 = W0s[c * FF + f], w1 = W1s[c * FF + f];
#pragma unroll
        for (int i = 0; i < 16; ++i) {
            float hv = rows[nq * 16 + i][c];
            gacc[i] = fmaf(hv, w1, gacc[i]);
            facc[i] = fmaf(hv, w0, facc[i]);
        }
    }
    const int j = b * FF + f, kk = n0 + nq * 16;
#pragma unroll
    for (int i = 0; i < 16; ++i)
        F0[(size_t)(kk + i) * NB + j] = facc[i];
    unsigned hw[8], lw[8];
#pragma unroll
    for (int q = 0; q < 8; ++q) {
        float v0 = gacc[2 * q], v1 = gacc[2 * q + 1];
        _Float16 h0 = (_Float16)v0, h1 = (_Float16)v1;
        _Float16 l0 = (_Float16)(v0 - (float)h0), l1 = (_Float16)(v1 - (float)h1);
        hw[q] = (unsigned)__builtin_bit_cast(ushort_t, h0) |
                ((unsigned)__builtin_bit_cast(ushort_t, h1) << 16);
        lw[q] = (unsigned)__builtin_bit_cast(ushort_t, l0) |
                ((unsigned)__builtin_bit_cast(ushort_t, l1) << 16);
    }
    uint4* gh = (uint4*)&Ght[(size_t)j * NN + kk];
    uint4* gl = (uint4*)&Glt[(size_t)j * NN + kk];
    gh[0] = make_uint4(hw[0], hw[1], hw[2], hw[3]);
    gh[1] = make_uint4(hw[4], hw[5], hw[6], hw[7]);
    gl[0] = make_uint4(lw[0], lw[1], lw[2], lw[3]);
    gl[1] = make_uint4(lw[4], lw[5], lw[6], lw[7]);
}

// ---------------- big GEMM via MFMA f16-split (planes, vector staging) ------
// Hp_z = Lhat[:, zK..] @ G[zK.., :], z==0 adds F0. 4 products (hh+hl+lh+ll).
// Both operands staged from [row][k] u16 planes with uint4 copies.
// Block 256 thr = 4 waves (2x2 of 32x32), tile 64x64, K-chunk 32 dbuf.
// grid (32, 8, 2) = 512 blocks.
__global__ __launch_bounds__(256) void k_prop_mfma(
        const ushort_t* __restrict__ Lhi, const ushort_t* __restrict__ Llo,
        const ushort_t* __restrict__ Ght, const ushort_t* __restrict__ Glt,
        const float* __restrict__ F0,
        float* __restrict__ Hp0, float* __restrict__ Hp1) {
    __shared__ ushort_t Ah[2][64][40], Al[2][64][40];
    __shared__ ushort_t Bh[2][64][40], Bl[2][64][40];
    const int tid  = threadIdx.x;
    const int lane = tid & 63, w = tid >> 6;
    const int wm = w >> 1, wn = w & 1;
    const int grp = lane >> 4, l16 = lane & 15;
    const int i0 = blockIdx.y * 64, j0 = blockIdx.x * 64;
    const int kbase = blockIdx.z * 256;
    const int sr = tid >> 2, sk = (tid & 3) * 8;   // stage: row 0..63, k {0,8,16,24}

    const ushort_t* pAh = Lhi + (size_t)(i0 + sr) * NN + kbase + sk;
    const ushort_t* pAl = Llo + (size_t)(i0 + sr) * NN + kbase + sk;
    const ushort_t* pBh = Ght + (size_t)(j0 + sr) * NN + kbase + sk;
    const ushort_t* pBl = Glt + (size_t)(j0 + sr) * NN + kbase + sk;

    f32x4 acc[2][2] = {};
    uint4 rah = *(const uint4*)pAh;
    uint4 ral = *(const uint4*)pAl;
    uint4 rbh = *(const uint4*)pBh;
    uint4 rbl = *(const uint4*)pBl;

    for (int t = 0; t < 8; ++t) {
        const int buf = t & 1;
        *(uint4*)&Ah[buf][sr][sk] = rah;
        *(uint4*)&Al[buf][sr][sk] = ral;
        *(uint4*)&Bh[buf][sr][sk] = rbh;
        *(uint4*)&Bl[buf][sr][sk] = rbl;
        __syncthreads();
        if (t < 7) {
            const int ko = (t + 1) * 32;
            rah = *(const uint4*)(pAh + ko);
            ral = *(const uint4*)(pAl + ko);
            rbh = *(const uint4*)(pBh + ko);
            rbl = *(const uint4*)(pBl + ko);
        }
        f16x8 ah[2], al[2], bh[2], bl[2];
#pragma unroll
        for (int mi = 0; mi < 2; ++mi) {
            ah[mi] = *(const f16x8*)&Ah[buf][wm * 32 + mi * 16 + l16][grp * 8];
            al[mi] = *(const f16x8*)&Al[buf][wm * 32 + mi * 16 + l16][grp * 8];
        }
#pragma unroll
        for (int ni = 0; ni < 2; ++ni) {
            bh[ni] = *(const f16x8*)&Bh[buf][wn * 32 + ni * 16 + l16][grp * 8];
            bl[ni] = *(const f16x8*)&Bl[buf][wn * 32 + ni * 16 + l16][grp * 8];
        }
#pragma unroll
        for (int mi = 0; mi < 2; ++mi)
#pragma unroll
            for (int ni = 0; ni < 2; ++ni) {
                acc[mi][ni] = __builtin_amdgcn_mfma_f32_16x16x32_f16(al[mi], bl[ni], acc[mi][ni], 0, 0, 0);
                acc[mi][ni] = __builtin_amdgcn_mfma_f32_16x16x32_f16(al[mi], bh[ni], acc[mi][ni], 0, 0, 0);
                acc[mi][ni] = __builtin_amdgcn_mfma_f32_16x16x32_f16(ah[mi], bl[ni], acc[mi][ni], 0, 0, 0);
                acc[mi][ni] = __builtin_amdgcn_mfma_f32_16x16x32_f16(ah[mi], bh[ni], acc[mi][ni], 0, 0, 0);
            }
        __syncthreads();
    }

    // epilogue: C/D layout col=lane&15, row=(lane>>4)*4+reg  (verified r9)
    float* Hp = blockIdx.z ? Hp1 : Hp0;
#pragma unroll
    for (int mi = 0; mi < 2; ++mi)
#pragma unroll
        for (int ni = 0; ni < 2; ++ni)
#pragma unroll
            for (int p = 0; p < 4; ++p) {
                const int row = i0 + wm * 32 + mi * 16 + grp * 4 + p;
                const int col = j0 + wn * 32 + ni * 16 + l16;
                const size_t idx = (size_t)row * NB + col;
                float v = acc[mi][ni][p];
                if (blockIdx.z == 0) v += F0[idx];
                Hp[idx] = v;
            }
}

// ---------------- FC1: A(64x16384) @ W(16384x256), K-split partials ---------
// A = Hp0+Hp1 (no relu after conv6). Writes P[kc][b][j]; reduced in k_fc23.
__global__ __launch_bounds__(256) void k_fc1(const float* __restrict__ h0,
                                             const float* __restrict__ h1,
                                             const float* __restrict__ W,
                                             float* __restrict__ P) {
    __shared__ float AT[128][68];      // AT[k][b]
    const int tid = threadIdx.x;
    const int jg = blockIdx.x;         // 0..7
    const int kc = blockIdx.y;         // 0..127
    const size_t base = (size_t)kc * 4 * NB;
#pragma unroll
    for (int i = 0; i < 8; ++i) {
        int q = tid + i * 256;         // float4 index, 0..2047
        float4 v0 = *(const float4*)&h0[base + q * 4];
        float4 v1 = *(const float4*)&h1[base + q * 4];
        float4 v;
        v.x = v0.x + v1.x; v.y = v0.y + v1.y;
        v.z = v0.z + v1.z; v.w = v0.w + v1.w;
        int flat = q * 4;
        int nn = flat >> 11, rem = flat & 2047;
        int b = rem >> 5, f0 = rem & 31;
        int krow = nn * 32 + f0;
        AT[krow + 0][b] = v.x; AT[krow + 1][b] = v.y;
        AT[krow + 2][b] = v.z; AT[krow + 3][b] = v.w;
    }
    __syncthreads();
    const int tj = tid & 31, bq = tid >> 5;
    float acc[8] = {};
    const float* wp = W + (size_t)(kc * 128) * 256 + jg * 32 + tj;
#pragma unroll 8
    for (int k = 0; k < 128; ++k) {
        float w = wp[(size_t)k * 256];
        const float* ap = &AT[k][bq * 8];
        float4 a0 = *(const float4*)ap;
        float4 a1 = *(const float4*)(ap + 4);
        acc[0] = fmaf(a0.x, w, acc[0]); acc[1] = fmaf(a0.y, w, acc[1]);
        acc[2] = fmaf(a0.z, w, acc[2]); acc[3] = fmaf(a0.w, w, acc[3]);
        acc[4] = fmaf(a1.x, w, acc[4]); acc[5] = fmaf(a1.y, w, acc[5]);
        acc[6] = fmaf(a1.z, w, acc[6]); acc[7] = fmaf(a1.w, w, acc[7]);
    }
#pragma unroll
    for (int b2 = 0; b2 < 8; ++b2)
        P[(size_t)kc * 16384 + (bq * 8 + b2) * 256 + jg * 32 + tj] = acc[b2];
}

// ---------------- fused reduce + FC2 + FC3 ----------------
__global__ __launch_bounds__(128) void k_fc23(const float* __restrict__ P,
        const float* __restrict__ b1, const float* __restrict__ W2,
        const float* __restrict__ b2, const float* __restrict__ W3,
        const float* __restrict__ b3, float* __restrict__ out) {
    __shared__ float row[256];
    __shared__ float r2[128];
    const int m = blockIdx.x, j = threadIdx.x;
#pragma unroll
    for (int rep = 0; rep < 2; ++rep) {
        int k2 = j + rep * 128;
        float s = b1[k2];
#pragma unroll 8
        for (int kc = 0; kc < 128; ++kc)
            s += P[(size_t)kc * 16384 + m * 256 + k2];
        row[k2] = s;
    }
    __syncthreads();
    float acc = b2[j];
#pragma unroll 4
    for (int k = 0; k < 256; ++k)
        acc = fmaf(row[k], W2[k * 128 + j], acc);
    r2[j] = acc;
    __syncthreads();
    const int w = j >> 6, l = j & 63;
    float s2 = r2[l] * W3[l * 2 + w] + r2[l + 64] * W3[(l + 64) * 2 + w];
#pragma unroll
    for (int off = 32; off > 0; off >>= 1)
        s2 += __shfl_down(s2, off);
    if (l == 0) out[m * 2 + w] = s2 + b3[w];
}

// ---------------- launch ----------------

extern "C" void kernel_launch(void* const* d_in, const int* in_sizes, int n_in,
                              void* d_out, int out_size, void* d_ws, size_t ws_size,
                              hipStream_t stream) {
    float* outp = (float*)d_out;
    if (ws_size < (size_t)WS_FLOATS * sizeof(float)) {
        k_zero_out<<<(out_size + 255) / 256, 256, 0, stream>>>(outp, out_size);
        return;
    }

    const float* x  = (const float*)d_in[0];
    const int*   ei = (const int*)d_in[1];
    const float* ew = (const float*)d_in[2];
    const float* cW[6] = {(const float*)d_in[3], (const float*)d_in[5],
                          (const float*)d_in[7], (const float*)d_in[9],
                          (const float*)d_in[11], (const float*)d_in[13]};
    const float* cb[6] = {(const float*)d_in[4], (const float*)d_in[6],
                          (const float*)d_in[8], (const float*)d_in[10],
                          (const float*)d_in[12], (const float*)d_in[14]};
    const float* fc1W = (const float*)d_in[15];
    const float* fc1b = (const float*)d_in[16];
    const float* fc2W = (const float*)d_in[17];
    const float* fc2b = (const float*)d_in[18];
    const float* fc3W = (const float*)d_in[19];
    const float* fc3b = (const float*)d_in[20];

    float*    ws   = (float*)d_ws;
    float*    Lhat = ws + OFF_LHAT;
    ushort_t* Lhi  = (ushort_t*)(ws + OFF_LHI);
    ushort_t* Llo  = (ushort_t*)(ws + OFF_LLO);
    float*    deg  = ws + OFF_DEG;
    float*    Hp0  = ws + OFF_HP0;
    float*    Hp1  = ws + OFF_HP1;
    ushort_t* Ght  = (ushort_t*)(ws + OFF_GHT);
    ushort_t* Glt  = (ushort_t*)(ws + OFF_GLT);
    float*    F0   = ws + OFF_F0;
    float*    P    = ws + OFF_P;

    // build dense Lhat, split to u16 hi/lo planes
    k_zero_range<<<(OFF_DEG + 512 + 255) / 256, 256, 0, stream>>>(ws, OFF_DEG + 512);
    k_deg<<<EE / 256, 256, 0, stream>>>(ei, ew, deg);
    k_dinv<<<1, 512, 0, stream>>>(deg);
    k_build<<<EE / 256, 256, 0, stream>>>(ei, ew, deg, Lhat);
    k_splitL<<<NN * NN / 256, 256, 0, stream>>>(Lhat, Lhi, Llo);

    dim3 sgrid(BB_, 4);        // (batch, node-group of 128)
    dim3 pgrid(32, 8, 2);
    // layer 1 (CIN=50, from x)
    k_small<TT, 0><<<sgrid, 256, 0, stream>>>(x, nullptr, cW[0], cb[0], Ght, Glt, F0);
    k_prop_mfma<<<pgrid, 256, 0, stream>>>(Lhi, Llo, Ght, Glt, F0, Hp0, Hp1);
    // layers 2..6 (consumer combines Hp0+Hp1 and applies relu)
    k_small<FF, 1><<<sgrid, 256, 0, stream>>>(Hp0, Hp1, cW[1], cb[1], Ght, Glt, F0);
    k_prop_mfma<<<pgrid, 256, 0, stream>>>(Lhi, Llo, Ght, Glt, F0, Hp0, Hp1);
    k_small<FF, 1><<<sgrid, 256, 0, stream>>>(Hp0, Hp1, cW[2], cb[2], Ght, Glt, F0);
    k_prop_mfma<<<pgrid, 256, 0, stream>>>(Lhi, Llo, Ght, Glt, F0, Hp0, Hp1);
    k_small<FF, 1><<<sgrid, 256, 0, stream>>>(Hp0, Hp1, cW[3], cb[3], Ght, Glt, F0);
    k_prop_mfma<<<pgrid, 256, 0, stream>>>(Lhi, Llo, Ght, Glt, F0, Hp0, Hp1);
    k_small<FF, 1><<<sgrid, 256, 0, stream>>>(Hp0, Hp1, cW[4], cb[4], Ght, Glt, F0);
    k_prop_mfma<<<pgrid, 256, 0, stream>>>(Lhi, Llo, Ght, Glt, F0, Hp0, Hp1);
    k_small<FF, 1><<<sgrid, 256, 0, stream>>>(Hp0, Hp1, cW[5], cb[5], Ght, Glt, F0);
    k_prop_mfma<<<pgrid, 256, 0, stream>>>(Lhi, Llo, Ght, Glt, F0, Hp0, Hp1);

    // FC head (fc1 combines Hp0+Hp1 without relu — matches reference)
    dim3 fgrid(8, 128);
    k_fc1<<<fgrid, 256, 0, stream>>>(Hp0, Hp1, fc1W, P);
    k_fc23<<<64, 128, 0, stream>>>(P, fc1b, fc2W, fc2b, fc3W, fc3b, outp);
}